// Round 19
// baseline (460.132 us; speedup 1.0000x reference)
//
#include <hip/hip_runtime.h>
#include <math.h>

#define NN 100000
#define NE 1600000
#define F_IN 602
#define H1 8
#define C1 8
#define F_MID 64   // H1*C1
#define NC 41
#define H2_LD 48   // padded h2 row: [0..40]=h2, [41]=asrc2
#define NEG_SLOPE 0.2f
#define WT_LD 640  // padded K for bf16 W1-transposed
#define GB1 ((NN + 63) / 64)          // 1563 gemm1 blocks
#define DGB 1024                      // deg/scatter grid-stride blocks
#define ATB ((NN * H1 + 255) / 256)   // 3125 attn1 blocks

#define LRELU(x) fmaxf((x), NEG_SLOPE * (x))

typedef __attribute__((ext_vector_type(8))) short short8;
typedef __attribute__((ext_vector_type(4))) float f32x4;

__device__ inline unsigned short f2bf(float f) {
    unsigned u = __builtin_bit_cast(unsigned, f);
    unsigned r = (u + 0x7FFFu + ((u >> 16) & 1u)) >> 16;
    return (unsigned short)r;
}
__device__ inline float bf2f(unsigned short u) {
    unsigned v = ((unsigned)u) << 16;
    return __builtin_bit_cast(float, v);
}

// -------- fused prep: W1 -> bf16 transposed padded [64][640]  +  zero deg --------
__global__ void prep_kernel(const float* __restrict__ W, unsigned short* __restrict__ Wt,
                            int4* __restrict__ degv, int ndeg4)
{
    int idx = blockIdx.x * blockDim.x + threadIdx.x;
    if (idx < F_MID * WT_LD) {
        int col = idx / WT_LD, k = idx % WT_LD;
        Wt[idx] = (k < F_IN) ? f2bf(W[k * F_MID + col]) : (unsigned short)0;
    } else {
        int z = idx - F_MID * WT_LD;
        if (z < ndeg4) degv[z] = make_int4(0, 0, 0, 0);
    }
}

// ---- MEGA1: deg-histogram+rank (blocks 0..DGB-1) ∥ gemm1 (BM=64, BK=64, reg-prefetch) ----
// 10 K-tiles: barrier pairs 19 -> 10, 8 MFMA per window. LDS 18.4KB, VGPR ~55.
__global__ __launch_bounds__(256) void mega1_kernel(
    const float* __restrict__ x, const unsigned short* __restrict__ Wt,
    unsigned short* __restrict__ h1b,
    const int* __restrict__ dst, int* __restrict__ deg, int* __restrict__ rank,
    int N, int E)
{
    __shared__ unsigned short As[64][72];  // stride 144B -> 2-way conflicts (free)
    __shared__ unsigned short Bs[64][72];

    int bid = blockIdx.x;
    int t = threadIdx.x;

    if (bid < DGB) {   // ---- deg path: rank[e] = old count ----
        for (int e = bid * 256 + t; e < E; e += DGB * 256)
            rank[e] = atomicAdd(&deg[dst[e]], 1);
        return;
    }

    // ---- gemm1 path ----
    int lane = t & 63;
    int w = t >> 6;
    int l16 = lane & 15, lg = lane >> 4;
    int n0 = (bid - DGB) * 64;

    // A staging: 4 threads/row, 16 consecutive k each
    int arow = t >> 2, aseg = t & 3;
    int grow = n0 + arow;
    const float* xrow = x + (size_t)(grow < N ? grow : 0) * F_IN + aseg * 16;
    // B staging: 4 threads/col, 16 consecutive k each (Wt zero-padded to 640)
    int bcol = t >> 2;
    const unsigned short* wrow = Wt + (size_t)bcol * WT_LD + aseg * 16;

    f32x4 acc[4] = {};
    float2 av[8];
    uint4  bv[2];

    // prologue: tile 0
    #pragma unroll
    for (int i = 0; i < 8; ++i) av[i] = *(const float2*)(xrow + i * 2);
    bv[0] = *(const uint4*)(wrow);
    bv[1] = *(const uint4*)(wrow + 8);

    for (int kt = 0; kt < 10; ++kt) {
        __syncthreads();
        {
            unsigned short tmp[16];
            #pragma unroll
            for (int i = 0; i < 8; ++i) {
                tmp[i * 2]     = f2bf(av[i].x);
                tmp[i * 2 + 1] = f2bf(av[i].y);
            }
            *(uint4*)(&As[arow][aseg * 16])     = ((const uint4*)tmp)[0];
            *(uint4*)(&As[arow][aseg * 16 + 8]) = ((const uint4*)tmp)[1];
            *(uint4*)(&Bs[bcol][aseg * 16])     = bv[0];
            *(uint4*)(&Bs[bcol][aseg * 16 + 8]) = bv[1];
        }
        __syncthreads();

        // issue next tile's loads (hidden under the 8 MFMA below)
        if (kt < 9) {
            int k0 = (kt + 1) * 64;
            if (kt + 1 < 9) {
                #pragma unroll
                for (int i = 0; i < 8; ++i) av[i] = *(const float2*)(xrow + k0 + i * 2);
            } else {        // tail tile: k 576..639, valid < 602
                #pragma unroll
                for (int i = 0; i < 8; ++i) {
                    int k = k0 + aseg * 16 + i * 2;
                    float a = (k < F_IN)     ? xrow[k0 + i * 2]     : 0.f;
                    float b = (k + 1 < F_IN) ? xrow[k0 + i * 2 + 1] : 0.f;
                    av[i] = make_float2(a, b);
                }
            }
            bv[0] = *(const uint4*)(wrow + k0);
            bv[1] = *(const uint4*)(wrow + k0 + 8);
        }

        #pragma unroll
        for (int ks = 0; ks < 2; ++ks) {
            short8 afrag = *(const short8*)(&As[w * 16 + l16][ks * 32 + lg * 8]);
            short8 bfrag[4];
            #pragma unroll
            for (int n = 0; n < 4; ++n)
                bfrag[n] = *(const short8*)(&Bs[n * 16 + l16][ks * 32 + lg * 8]);
            #pragma unroll
            for (int n = 0; n < 4; ++n)
                acc[n] = __builtin_amdgcn_mfma_f32_16x16x32_bf16(afrag, bfrag[n], acc[n], 0, 0, 0);
        }
    }

    // epilogue: C/D layout col=lane&15, row=(lane>>4)*4+reg; store bf16
    #pragma unroll
    for (int r = 0; r < 4; ++r) {
        int row = n0 + w * 16 + lg * 4 + r;
        if (row < N) {
            #pragma unroll
            for (int n = 0; n < 4; ++n)
                h1b[(size_t)row * F_MID + n * 16 + l16] = f2bf(acc[n][r]);
        }
    }
}

// ---------------- hierarchical scan ----------------
__global__ void scan1_kernel(const int* __restrict__ deg, int* __restrict__ bsum, int N)
{
    int b = blockIdx.x, t = threadIdx.x;
    int base = b * 1024 + t * 16;
    int s = 0;
    #pragma unroll
    for (int i = 0; i < 16; ++i) { int idx = base + i; if (idx < N) s += deg[idx]; }
    #pragma unroll
    for (int o = 32; o > 0; o >>= 1) s += __shfl_down(s, o);
    if (t == 0) bsum[b] = s;
}

__global__ void scan2_kernel(const int* __restrict__ bsum, int* __restrict__ boff,
                             int nb, int* __restrict__ offs, int N, int E)
{
    __shared__ int buf[128];
    int t = threadIdx.x;
    int v = (t < nb) ? bsum[t] : 0;
    buf[t] = v;
    __syncthreads();
    for (int o = 1; o < 128; o <<= 1) {
        int u = (t >= o) ? buf[t - o] : 0;
        __syncthreads();
        buf[t] += u;
        __syncthreads();
    }
    if (t < nb) boff[t] = buf[t] - v;    // exclusive
    if (t == 0) offs[N] = E;
}

__global__ void scan3_kernel(const int* __restrict__ deg, const int* __restrict__ boff,
                             int* __restrict__ offs, int N)
{
    int b = blockIdx.x, t = threadIdx.x;
    int base = b * 1024 + t * 16;
    int loc[16];
    int s = 0;
    #pragma unroll
    for (int i = 0; i < 16; ++i) {
        int idx = base + i;
        loc[i] = (idx < N) ? deg[idx] : 0;
        s += loc[i];
    }
    int inc = s;
    #pragma unroll
    for (int o = 1; o < 64; o <<= 1) {
        int u = __shfl_up(inc, o);
        if (t >= o) inc += u;
    }
    int run = inc - s + boff[b];
    #pragma unroll
    for (int i = 0; i < 16; ++i) {
        int idx = base + i;
        if (idx < N) offs[idx] = run;
        run += loc[i];
    }
}

// ---- MEGA2: rank-based scatter (atomic-free) ∥ attn1 (adst only — asrc computed in agg1) ----
__global__ void mega2_kernel(
    const unsigned short* __restrict__ h1b,
    const float* __restrict__ attD,
    float* __restrict__ adst,
    const int* __restrict__ src, const int* __restrict__ dst,
    const int* __restrict__ rank, const int* __restrict__ offs,
    int* __restrict__ srcs, int N, int E)
{
    int bid = blockIdx.x, t = threadIdx.x;
    if (bid < DGB) {   // scatter
        for (int e = bid * 256 + t; e < E; e += DGB * 256)
            srcs[offs[dst[e]] + rank[e]] = src[e];
        return;
    }
    int idx = (bid - DGB) * 256 + t;   // n*8 + head
    if (idx >= N * H1) return;
    int n = idx >> 3, hh = idx & 7;
    float d = 0.f;
    #pragma unroll
    for (int c = 0; c < C1; ++c)
        d += bf2f(h1b[n * F_MID + hh * C1 + c]) * attD[hh * C1 + c];
    adst[idx] = d;
}

// ------- layer-1 agg + ELU: one wave/node, online softmax, 8-edge batches, bf16 gather,
//         asrc computed IN-WAVE from the gathered row -------
__global__ void agg1_kernel(const int* __restrict__ offs, const int* __restrict__ srcs,
                            const unsigned short* __restrict__ h1b,
                            const float* __restrict__ attS,
                            const float* __restrict__ adst,
                            const float* __restrict__ b1,
                            float* __restrict__ out1, int N)
{
    int wave = (blockIdx.x * blockDim.x + threadIdx.x) >> 6;
    int lane = threadIdx.x & 63;
    if (wave >= N) return;
    int n = wave;
    int hh = lane >> 3;                 // head
    int beg = offs[n], end = offs[n + 1];
    float ad = adst[n * H1 + hh];
    float attv = attS[lane];            // attS1 flat [hh][c] == lane

    float m = -INFINITY, den = 0.f, acc = 0.f;
    int i = beg;
    for (; i + 8 <= end; i += 8) {
        int s[8];
        #pragma unroll
        for (int j = 0; j < 8; ++j) s[j] = srcs[i + j];
        float v[8];
        #pragma unroll
        for (int j = 0; j < 8; ++j) v[j] = bf2f(h1b[(size_t)s[j] * F_MID + lane]);
        float e[8];
        #pragma unroll
        for (int j = 0; j < 8; ++j) {
            float tt = v[j] * attv;          // in-wave asrc: 8-lane head-group reduce
            tt += __shfl_xor(tt, 1);
            tt += __shfl_xor(tt, 2);
            tt += __shfl_xor(tt, 4);
            e[j] = LRELU(tt + ad);
        }
        float m8 = fmaxf(fmaxf(fmaxf(e[0], e[1]), fmaxf(e[2], e[3])),
                         fmaxf(fmaxf(e[4], e[5]), fmaxf(e[6], e[7])));
        float mn = fmaxf(m, m8);
        float sc = __expf(m - mn);
        float p[8];
        #pragma unroll
        for (int j = 0; j < 8; ++j) p[j] = __expf(e[j] - mn);
        den = den * sc + (((p[0] + p[1]) + (p[2] + p[3])) + ((p[4] + p[5]) + (p[6] + p[7])));
        acc = acc * sc + (((p[0] * v[0] + p[1] * v[1]) + (p[2] * v[2] + p[3] * v[3]))
                        + ((p[4] * v[4] + p[5] * v[5]) + (p[6] * v[6] + p[7] * v[7])));
        m = mn;
    }
    for (; i < end; ++i) {
        int s = srcs[i];
        float hv = bf2f(h1b[(size_t)s * F_MID + lane]);
        float tt = hv * attv;
        tt += __shfl_xor(tt, 1);
        tt += __shfl_xor(tt, 2);
        tt += __shfl_xor(tt, 4);
        float e = LRELU(tt + ad);
        float mn = fmaxf(m, e);
        float sc = __expf(m - mn);
        float p  = __expf(e - mn);
        den = den * sc + p;
        acc = acc * sc + p * hv;
        m = mn;
    }
    float inv = 1.f / (den + 1e-16f);
    float v = acc * inv + b1[lane];
    out1[n * F_MID + lane] = v > 0.f ? v : expm1f(v);   // ELU
}

// ---------------- GEMM2: h2p = out1 @ W2  [N,64]x[64,41], row stride 48 ----------------
__global__ __launch_bounds__(256) void gemm2_kernel(
    const float* __restrict__ out1, const float* __restrict__ W2,
    float* __restrict__ h2p, int N)
{
    __shared__ float ws[F_MID * NC];
    for (int i = threadIdx.x; i < F_MID * NC; i += 256) ws[i] = W2[i];
    __syncthreads();
    int idx = blockIdx.x * blockDim.x + threadIdx.x;
    if (idx >= N * NC) return;
    int n = idx / NC, j = idx % NC;
    const float* row = out1 + n * F_MID;
    float acc = 0.f;
    #pragma unroll
    for (int k = 0; k < F_MID; ++k) acc += row[k] * ws[k * NC + j];
    h2p[(size_t)n * H2_LD + j] = acc;
}

// attn2: thread-per-node (measured-fast form). asrc -> h2p[n*48+41], adst separate
__global__ void attn2_kernel(float* __restrict__ h2p,
                             const float* __restrict__ attS,
                             const float* __restrict__ attD,
                             float* __restrict__ adst, int N)
{
    int n = blockIdx.x * blockDim.x + threadIdx.x;
    if (n >= N) return;
    float s = 0.f, d = 0.f;
    #pragma unroll
    for (int j = 0; j < NC; ++j) {
        float v = h2p[(size_t)n * H2_LD + j];
        s += v * attS[j];
        d += v * attD[j];
    }
    h2p[(size_t)n * H2_LD + NC] = s;
    adst[n] = d;
}

// ------- layer-2 agg + log_softmax: packed rows, 8-edge batches -------
__global__ void agg2_kernel(const int* __restrict__ offs, const int* __restrict__ srcs,
                            const float* __restrict__ h2p,
                            const float* __restrict__ adst,
                            const float* __restrict__ b2,
                            float* __restrict__ out, int N)
{
    int wave = (blockIdx.x * blockDim.x + threadIdx.x) >> 6;
    int lane = threadIdx.x & 63;
    if (wave >= N) return;
    int n = wave;
    int beg = offs[n], end = offs[n + 1];
    float ad = adst[n];
    bool act = lane < NC;
    int li = act ? lane : NC;           // lanes >=41 read the asrc slot

    float m = -INFINITY, den = 0.f, acc = 0.f;
    int i = beg;
    for (; i + 8 <= end; i += 8) {
        int s[8];
        #pragma unroll
        for (int j = 0; j < 8; ++j) s[j] = srcs[i + j];
        float hv[8];
        #pragma unroll
        for (int j = 0; j < 8; ++j) hv[j] = h2p[(size_t)s[j] * H2_LD + li];
        float a[8];
        #pragma unroll
        for (int j = 0; j < 8; ++j) a[j] = __shfl(hv[j], NC);  // broadcast asrc from lane 41
        float e[8];
        #pragma unroll
        for (int j = 0; j < 8; ++j) e[j] = LRELU(a[j] + ad);
        float m8 = fmaxf(fmaxf(fmaxf(e[0], e[1]), fmaxf(e[2], e[3])),
                         fmaxf(fmaxf(e[4], e[5]), fmaxf(e[6], e[7])));
        float mn = fmaxf(m, m8);
        float sc = __expf(m - mn);
        float p[8];
        #pragma unroll
        for (int j = 0; j < 8; ++j) p[j] = __expf(e[j] - mn);
        den = den * sc + (((p[0] + p[1]) + (p[2] + p[3])) + ((p[4] + p[5]) + (p[6] + p[7])));
        acc = acc * sc + (((p[0] * hv[0] + p[1] * hv[1]) + (p[2] * hv[2] + p[3] * hv[3]))
                        + ((p[4] * hv[4] + p[5] * hv[5]) + (p[6] * hv[6] + p[7] * hv[7])));
        m = mn;
    }
    for (; i < end; ++i) {
        int s = srcs[i];
        float hv = h2p[(size_t)s * H2_LD + li];
        float a = __shfl(hv, NC);
        float e = LRELU(a + ad);
        float mn = fmaxf(m, e);
        float sc = __expf(m - mn);
        float p  = __expf(e - mn);
        den = den * sc + p;
        acc = acc * sc + p * hv;
        m = mn;
    }
    float inv = 1.f / (den + 1e-16f);
    float v = act ? acc * inv + b2[lane] : -INFINITY;
    float mm = v;
    #pragma unroll
    for (int o = 32; o > 0; o >>= 1) mm = fmaxf(mm, __shfl_xor(mm, o));
    float ex = act ? __expf(v - mm) : 0.f;
    float S = ex;
    #pragma unroll
    for (int o = 32; o > 0; o >>= 1) S += __shfl_xor(S, o);
    if (act) out[n * NC + lane] = v - mm - logf(S);
}

// ---------------- launch ----------------
extern "C" void kernel_launch(void* const* d_in, const int* in_sizes, int n_in,
                              void* d_out, int out_size, void* d_ws, size_t ws_size,
                              hipStream_t stream)
{
    const float* x     = (const float*)d_in[0];
    const int*   ei    = (const int*)  d_in[1];
    const float* W1    = (const float*)d_in[2];
    const float* attS1 = (const float*)d_in[3];
    const float* attD1 = (const float*)d_in[4];
    const float* b1    = (const float*)d_in[5];
    const float* W2    = (const float*)d_in[6];
    const float* attS2 = (const float*)d_in[7];
    const float* attD2 = (const float*)d_in[8];
    const float* b2    = (const float*)d_in[9];
    float* out = (float*)d_out;

    const int N = NN, E = NE;
    const int* src = ei;        // edge_index row 0
    const int* dst = ei + E;    // edge_index row 1

    char* p = (char*)d_ws;
    auto alloc = [&](size_t bytes) { char* r = p; p += (bytes + 255) & ~255ull; return r; };
    unsigned short* h1b = (unsigned short*)alloc((size_t)N * F_MID * 2);
    float* adst1 = (float*)alloc((size_t)N * H1 * 4);
    float* out1  = (float*)alloc((size_t)N * F_MID * 4);
    float* h2p   = (float*)alloc((size_t)N * H2_LD * 4);   // [41]=asrc2
    float* adst2 = (float*)alloc((size_t)N * 4);
    int*   deg   = (int*)alloc((size_t)N * 4);
    int*   rank  = (int*)alloc((size_t)E * 4);
    int*   offs  = (int*)alloc((size_t)(N + 1) * 4);
    int*   srcs  = (int*)alloc((size_t)E * 4);
    unsigned short* Wt = (unsigned short*)alloc((size_t)F_MID * WT_LD * 2);
    const int NB = (N + 1023) / 1024;                 // 98 scan blocks
    int*   bsum  = (int*)alloc((size_t)NB * 4);
    int*   boff  = (int*)alloc((size_t)NB * 4);

    const int ndeg4 = N / 4;
    prep_kernel<<<(F_MID * WT_LD + ndeg4 + 255) / 256, 256, 0, stream>>>(
        W1, Wt, (int4*)deg, ndeg4);
    mega1_kernel<<<DGB + GB1, 256, 0, stream>>>(x, Wt, h1b, dst, deg, rank, N, E);
    scan1_kernel<<<NB, 64, 0, stream>>>(deg, bsum, N);
    scan2_kernel<<<1, 128, 0, stream>>>(bsum, boff, NB, offs, N, E);
    scan3_kernel<<<NB, 64, 0, stream>>>(deg, boff, offs, N);
    mega2_kernel<<<DGB + ATB, 256, 0, stream>>>(
        h1b, attD1, adst1, src, dst, rank, offs, srcs, N, E);
    agg1_kernel<<<(N * 64 + 255) / 256, 256, 0, stream>>>(
        offs, srcs, h1b, attS1, adst1, b1, out1, N);
    gemm2_kernel<<<(N * NC + 255) / 256, 256, 0, stream>>>(out1, W2, h2p, N);
    attn2_kernel<<<(N + 255) / 256, 256, 0, stream>>>(h2p, attS2, attD2, adst2, N);
    agg2_kernel<<<(N * 64 + 255) / 256, 256, 0, stream>>>(offs, srcs, h2p, adst2, b2, out, N);
}

// Round 20
// 413.084 us; speedup vs baseline: 1.1139x; 1.1139x over previous
//
#include <hip/hip_runtime.h>
#include <math.h>

#define NN 100000
#define NE 1600000
#define F_IN 602
#define H1 8
#define C1 8
#define F_MID 64   // H1*C1
#define NC 41
#define H2_LD 48   // padded h2 row: [0..40]=h2, [41]=asrc2
#define NEG_SLOPE 0.2f
#define WT_LD 640  // padded K for bf16 W1-transposed
#define GB1 ((NN + 63) / 64)          // 1563 gemm1 blocks
#define DGB 1024                      // deg/scatter grid-stride blocks
#define ATB ((NN * H1 + 255) / 256)   // 3125 attn1 blocks

#define LRELU(x) fmaxf((x), NEG_SLOPE * (x))

typedef __attribute__((ext_vector_type(8))) short short8;
typedef __attribute__((ext_vector_type(4))) float f32x4;

__device__ inline unsigned short f2bf(float f) {
    unsigned u = __builtin_bit_cast(unsigned, f);
    unsigned r = (u + 0x7FFFu + ((u >> 16) & 1u)) >> 16;
    return (unsigned short)r;
}
__device__ inline float bf2f(unsigned short u) {
    unsigned v = ((unsigned)u) << 16;
    return __builtin_bit_cast(float, v);
}

// ---------------- zero deg ----------------
__global__ void zero_kernel(int4* __restrict__ p, int n4)
{
    int i = blockIdx.x * blockDim.x + threadIdx.x;
    if (i < n4) p[i] = make_int4(0, 0, 0, 0);
}

// -------- prep: W1 -> bf16 transposed padded [64][640] --------
__global__ void prep_wt_kernel(const float* __restrict__ W, unsigned short* __restrict__ Wt)
{
    int idx = blockIdx.x * blockDim.x + threadIdx.x;
    if (idx >= F_MID * WT_LD) return;
    int col = idx / WT_LD, k = idx % WT_LD;
    Wt[idx] = (k < F_IN) ? f2bf(W[k * F_MID + col]) : (unsigned short)0;
}

// ---- MEGA1: deg-histogram+rank (blocks 0..DGB-1) ∥ gemm1 (R13 form: BM=64, BK=32) ----
__global__ __launch_bounds__(256) void mega1_kernel(
    const float* __restrict__ x, const unsigned short* __restrict__ Wt,
    unsigned short* __restrict__ h1b,
    const int* __restrict__ dst, int* __restrict__ deg, int* __restrict__ rank,
    int N, int E)
{
    __shared__ unsigned short As[64][40];  // stride 80B -> <=2-way conflicts
    __shared__ unsigned short Bs[64][40];

    int bid = blockIdx.x;
    int t = threadIdx.x;

    if (bid < DGB) {   // ---- deg path: rank[e] = old count ----
        for (int e = bid * 256 + t; e < E; e += DGB * 256)
            rank[e] = atomicAdd(&deg[dst[e]], 1);
        return;
    }

    // ---- gemm1 path ----
    int lane = t & 63;
    int w = t >> 6;
    int l16 = lane & 15, lg = lane >> 4;
    int n0 = (bid - DGB) * 64;

    int arow = t >> 2, aseg = t & 3;
    int grow = n0 + arow;
    const float* xrow = x + (size_t)(grow < N ? grow : 0) * F_IN + aseg * 8;
    int bcol = t >> 2;
    const unsigned short* wrow = Wt + (size_t)bcol * WT_LD + aseg * 8;

    f32x4 acc[4] = {};
    float2 av[4];
    uint4  bv;

    #pragma unroll
    for (int i = 0; i < 4; ++i) av[i] = *(const float2*)(xrow + i * 2);
    bv = *(const uint4*)(wrow);

    for (int kt = 0; kt < 19; ++kt) {
        __syncthreads();
        {
            unsigned short tmp[8];
            #pragma unroll
            for (int i = 0; i < 4; ++i) {
                tmp[i * 2]     = f2bf(av[i].x);
                tmp[i * 2 + 1] = f2bf(av[i].y);
            }
            *(uint4*)(&As[arow][aseg * 8]) = *(uint4*)tmp;
            *(uint4*)(&Bs[bcol][aseg * 8]) = bv;
        }
        __syncthreads();

        if (kt < 18) {
            int k0 = (kt + 1) * 32;
            if (kt + 1 < 18) {
                #pragma unroll
                for (int i = 0; i < 4; ++i) av[i] = *(const float2*)(xrow + k0 + i * 2);
            } else {
                #pragma unroll
                for (int i = 0; i < 4; ++i) {
                    int k = k0 + aseg * 8 + i * 2;
                    float a = (k < F_IN)     ? xrow[k0 + i * 2]     : 0.f;
                    float b = (k + 1 < F_IN) ? xrow[k0 + i * 2 + 1] : 0.f;
                    av[i] = make_float2(a, b);
                }
            }
            bv = *(const uint4*)(wrow + k0);
        }

        short8 afrag = *(const short8*)(&As[w * 16 + l16][lg * 8]);
        short8 bfrag[4];
        #pragma unroll
        for (int n = 0; n < 4; ++n)
            bfrag[n] = *(const short8*)(&Bs[n * 16 + l16][lg * 8]);
        #pragma unroll
        for (int n = 0; n < 4; ++n)
            acc[n] = __builtin_amdgcn_mfma_f32_16x16x32_bf16(afrag, bfrag[n], acc[n], 0, 0, 0);
    }

    #pragma unroll
    for (int r = 0; r < 4; ++r) {
        int row = n0 + w * 16 + lg * 4 + r;
        if (row < N) {
            #pragma unroll
            for (int n = 0; n < 4; ++n)
                h1b[(size_t)row * F_MID + n * 16 + l16] = f2bf(acc[n][r]);
        }
    }
}

// ---------------- hierarchical scan ----------------
__global__ void scan1_kernel(const int* __restrict__ deg, int* __restrict__ bsum, int N)
{
    int b = blockIdx.x, t = threadIdx.x;
    int base = b * 1024 + t * 16;
    int s = 0;
    #pragma unroll
    for (int i = 0; i < 16; ++i) { int idx = base + i; if (idx < N) s += deg[idx]; }
    #pragma unroll
    for (int o = 32; o > 0; o >>= 1) s += __shfl_down(s, o);
    if (t == 0) bsum[b] = s;
}

__global__ void scan2_kernel(const int* __restrict__ bsum, int* __restrict__ boff,
                             int nb, int* __restrict__ offs, int N, int E)
{
    __shared__ int buf[128];
    int t = threadIdx.x;
    int v = (t < nb) ? bsum[t] : 0;
    buf[t] = v;
    __syncthreads();
    for (int o = 1; o < 128; o <<= 1) {
        int u = (t >= o) ? buf[t - o] : 0;
        __syncthreads();
        buf[t] += u;
        __syncthreads();
    }
    if (t < nb) boff[t] = buf[t] - v;    // exclusive
    if (t == 0) offs[N] = E;
}

__global__ void scan3_kernel(const int* __restrict__ deg, const int* __restrict__ boff,
                             int* __restrict__ offs, int N)
{
    int b = blockIdx.x, t = threadIdx.x;
    int base = b * 1024 + t * 16;
    int loc[16];
    int s = 0;
    #pragma unroll
    for (int i = 0; i < 16; ++i) {
        int idx = base + i;
        loc[i] = (idx < N) ? deg[idx] : 0;
        s += loc[i];
    }
    int inc = s;
    #pragma unroll
    for (int o = 1; o < 64; o <<= 1) {
        int u = __shfl_up(inc, o);
        if (t >= o) inc += u;
    }
    int run = inc - s + boff[b];
    #pragma unroll
    for (int i = 0; i < 16; ++i) {
        int idx = base + i;
        if (idx < N) offs[idx] = run;
        run += loc[i];
    }
}

// ---- MEGA2: rank-based scatter (atomic-free) ∥ attn1 (adst only — asrc computed in agg1) ----
__global__ void mega2_kernel(
    const unsigned short* __restrict__ h1b,
    const float* __restrict__ attD,
    float* __restrict__ adst,
    const int* __restrict__ src, const int* __restrict__ dst,
    const int* __restrict__ rank, const int* __restrict__ offs,
    int* __restrict__ srcs, int N, int E)
{
    int bid = blockIdx.x, t = threadIdx.x;
    if (bid < DGB) {   // scatter
        for (int e = bid * 256 + t; e < E; e += DGB * 256)
            srcs[offs[dst[e]] + rank[e]] = src[e];
        return;
    }
    int idx = (bid - DGB) * 256 + t;   // n*8 + head
    if (idx >= N * H1) return;
    int n = idx >> 3, hh = idx & 7;
    float d = 0.f;
    #pragma unroll
    for (int c = 0; c < C1; ++c)
        d += bf2f(h1b[n * F_MID + hh * C1 + c]) * attD[hh * C1 + c];
    adst[idx] = d;
}

// ------- layer-1 agg + ELU: one wave/node, online softmax, 8-edge batches, bf16 gather,
//         asrc computed IN-WAVE from the gathered row -------
__global__ void agg1_kernel(const int* __restrict__ offs, const int* __restrict__ srcs,
                            const unsigned short* __restrict__ h1b,
                            const float* __restrict__ attS,
                            const float* __restrict__ adst,
                            const float* __restrict__ b1,
                            float* __restrict__ out1, int N)
{
    int wave = (blockIdx.x * blockDim.x + threadIdx.x) >> 6;
    int lane = threadIdx.x & 63;
    if (wave >= N) return;
    int n = wave;
    int hh = lane >> 3;                 // head
    int beg = offs[n], end = offs[n + 1];
    float ad = adst[n * H1 + hh];
    float attv = attS[lane];            // attS1 flat [hh][c] == lane

    float m = -INFINITY, den = 0.f, acc = 0.f;
    int i = beg;
    for (; i + 8 <= end; i += 8) {
        int s[8];
        #pragma unroll
        for (int j = 0; j < 8; ++j) s[j] = srcs[i + j];
        float v[8];
        #pragma unroll
        for (int j = 0; j < 8; ++j) v[j] = bf2f(h1b[(size_t)s[j] * F_MID + lane]);
        float e[8];
        #pragma unroll
        for (int j = 0; j < 8; ++j) {
            float tt = v[j] * attv;          // in-wave asrc: 8-lane head-group reduce
            tt += __shfl_xor(tt, 1);
            tt += __shfl_xor(tt, 2);
            tt += __shfl_xor(tt, 4);
            e[j] = LRELU(tt + ad);
        }
        float m8 = fmaxf(fmaxf(fmaxf(e[0], e[1]), fmaxf(e[2], e[3])),
                         fmaxf(fmaxf(e[4], e[5]), fmaxf(e[6], e[7])));
        float mn = fmaxf(m, m8);
        float sc = __expf(m - mn);
        float p[8];
        #pragma unroll
        for (int j = 0; j < 8; ++j) p[j] = __expf(e[j] - mn);
        den = den * sc + (((p[0] + p[1]) + (p[2] + p[3])) + ((p[4] + p[5]) + (p[6] + p[7])));
        acc = acc * sc + (((p[0] * v[0] + p[1] * v[1]) + (p[2] * v[2] + p[3] * v[3]))
                        + ((p[4] * v[4] + p[5] * v[5]) + (p[6] * v[6] + p[7] * v[7])));
        m = mn;
    }
    for (; i < end; ++i) {
        int s = srcs[i];
        float hv = bf2f(h1b[(size_t)s * F_MID + lane]);
        float tt = hv * attv;
        tt += __shfl_xor(tt, 1);
        tt += __shfl_xor(tt, 2);
        tt += __shfl_xor(tt, 4);
        float e = LRELU(tt + ad);
        float mn = fmaxf(m, e);
        float sc = __expf(m - mn);
        float p  = __expf(e - mn);
        den = den * sc + p;
        acc = acc * sc + p * hv;
        m = mn;
    }
    float inv = 1.f / (den + 1e-16f);
    float v = acc * inv + b1[lane];
    out1[n * F_MID + lane] = v > 0.f ? v : expm1f(v);   // ELU
}

// ---------------- GEMM2: h2p = out1 @ W2  [N,64]x[64,41], row stride 48 ----------------
__global__ __launch_bounds__(256) void gemm2_kernel(
    const float* __restrict__ out1, const float* __restrict__ W2,
    float* __restrict__ h2p, int N)
{
    __shared__ float ws[F_MID * NC];
    for (int i = threadIdx.x; i < F_MID * NC; i += 256) ws[i] = W2[i];
    __syncthreads();
    int idx = blockIdx.x * blockDim.x + threadIdx.x;
    if (idx >= N * NC) return;
    int n = idx / NC, j = idx % NC;
    const float* row = out1 + n * F_MID;
    float acc = 0.f;
    #pragma unroll
    for (int k = 0; k < F_MID; ++k) acc += row[k] * ws[k * NC + j];
    h2p[(size_t)n * H2_LD + j] = acc;
}

// attn2: thread-per-node. asrc -> h2p[n*48+41], adst separate
__global__ void attn2_kernel(float* __restrict__ h2p,
                             const float* __restrict__ attS,
                             const float* __restrict__ attD,
                             float* __restrict__ adst, int N)
{
    int n = blockIdx.x * blockDim.x + threadIdx.x;
    if (n >= N) return;
    float s = 0.f, d = 0.f;
    #pragma unroll
    for (int j = 0; j < NC; ++j) {
        float v = h2p[(size_t)n * H2_LD + j];
        s += v * attS[j];
        d += v * attD[j];
    }
    h2p[(size_t)n * H2_LD + NC] = s;
    adst[n] = d;
}

// ------- layer-2 agg + log_softmax: packed rows, 8-edge batches -------
__global__ void agg2_kernel(const int* __restrict__ offs, const int* __restrict__ srcs,
                            const float* __restrict__ h2p,
                            const float* __restrict__ adst,
                            const float* __restrict__ b2,
                            float* __restrict__ out, int N)
{
    int wave = (blockIdx.x * blockDim.x + threadIdx.x) >> 6;
    int lane = threadIdx.x & 63;
    if (wave >= N) return;
    int n = wave;
    int beg = offs[n], end = offs[n + 1];
    float ad = adst[n];
    bool act = lane < NC;
    int li = act ? lane : NC;           // lanes >=41 read the asrc slot

    float m = -INFINITY, den = 0.f, acc = 0.f;
    int i = beg;
    for (; i + 8 <= end; i += 8) {
        int s[8];
        #pragma unroll
        for (int j = 0; j < 8; ++j) s[j] = srcs[i + j];
        float hv[8];
        #pragma unroll
        for (int j = 0; j < 8; ++j) hv[j] = h2p[(size_t)s[j] * H2_LD + li];
        float a[8];
        #pragma unroll
        for (int j = 0; j < 8; ++j) a[j] = __shfl(hv[j], NC);  // broadcast asrc from lane 41
        float e[8];
        #pragma unroll
        for (int j = 0; j < 8; ++j) e[j] = LRELU(a[j] + ad);
        float m8 = fmaxf(fmaxf(fmaxf(e[0], e[1]), fmaxf(e[2], e[3])),
                         fmaxf(fmaxf(e[4], e[5]), fmaxf(e[6], e[7])));
        float mn = fmaxf(m, m8);
        float sc = __expf(m - mn);
        float p[8];
        #pragma unroll
        for (int j = 0; j < 8; ++j) p[j] = __expf(e[j] - mn);
        den = den * sc + (((p[0] + p[1]) + (p[2] + p[3])) + ((p[4] + p[5]) + (p[6] + p[7])));
        acc = acc * sc + (((p[0] * hv[0] + p[1] * hv[1]) + (p[2] * hv[2] + p[3] * hv[3]))
                        + ((p[4] * hv[4] + p[5] * hv[5]) + (p[6] * hv[6] + p[7] * hv[7])));
        m = mn;
    }
    for (; i < end; ++i) {
        int s = srcs[i];
        float hv = h2p[(size_t)s * H2_LD + li];
        float a = __shfl(hv, NC);
        float e = LRELU(a + ad);
        float mn = fmaxf(m, e);
        float sc = __expf(m - mn);
        float p  = __expf(e - mn);
        den = den * sc + p;
        acc = acc * sc + p * hv;
        m = mn;
    }
    float inv = 1.f / (den + 1e-16f);
    float v = act ? acc * inv + b2[lane] : -INFINITY;
    float mm = v;
    #pragma unroll
    for (int o = 32; o > 0; o >>= 1) mm = fmaxf(mm, __shfl_xor(mm, o));
    float ex = act ? __expf(v - mm) : 0.f;
    float S = ex;
    #pragma unroll
    for (int o = 32; o > 0; o >>= 1) S += __shfl_xor(S, o);
    if (act) out[n * NC + lane] = v - mm - logf(S);
}

// ---------------- launch ----------------
extern "C" void kernel_launch(void* const* d_in, const int* in_sizes, int n_in,
                              void* d_out, int out_size, void* d_ws, size_t ws_size,
                              hipStream_t stream)
{
    const float* x     = (const float*)d_in[0];
    const int*   ei    = (const int*)  d_in[1];
    const float* W1    = (const float*)d_in[2];
    const float* attS1 = (const float*)d_in[3];
    const float* attD1 = (const float*)d_in[4];
    const float* b1    = (const float*)d_in[5];
    const float* W2    = (const float*)d_in[6];
    const float* attS2 = (const float*)d_in[7];
    const float* attD2 = (const float*)d_in[8];
    const float* b2    = (const float*)d_in[9];
    float* out = (float*)d_out;

    const int N = NN, E = NE;
    const int* src = ei;        // edge_index row 0
    const int* dst = ei + E;    // edge_index row 1

    char* p = (char*)d_ws;
    auto alloc = [&](size_t bytes) { char* r = p; p += (bytes + 255) & ~255ull; return r; };
    unsigned short* h1b = (unsigned short*)alloc((size_t)N * F_MID * 2);
    float* adst1 = (float*)alloc((size_t)N * H1 * 4);
    float* out1  = (float*)alloc((size_t)N * F_MID * 4);
    float* h2p   = (float*)alloc((size_t)N * H2_LD * 4);   // [41]=asrc2
    float* adst2 = (float*)alloc((size_t)N * 4);
    int*   deg   = (int*)alloc((size_t)N * 4);
    int*   rank  = (int*)alloc((size_t)E * 4);
    int*   offs  = (int*)alloc((size_t)(N + 1) * 4);
    int*   srcs  = (int*)alloc((size_t)E * 4);
    unsigned short* Wt = (unsigned short*)alloc((size_t)F_MID * WT_LD * 2);
    const int NB = (N + 1023) / 1024;                 // 98 scan blocks
    int*   bsum  = (int*)alloc((size_t)NB * 4);
    int*   boff  = (int*)alloc((size_t)NB * 4);

    zero_kernel<<<(N / 4 + 255) / 256, 256, 0, stream>>>((int4*)deg, N / 4);
    prep_wt_kernel<<<(F_MID * WT_LD + 255) / 256, 256, 0, stream>>>(W1, Wt);
    mega1_kernel<<<DGB + GB1, 256, 0, stream>>>(x, Wt, h1b, dst, deg, rank, N, E);
    scan1_kernel<<<NB, 64, 0, stream>>>(deg, bsum, N);
    scan2_kernel<<<1, 128, 0, stream>>>(bsum, boff, NB, offs, N, E);
    scan3_kernel<<<NB, 64, 0, stream>>>(deg, boff, offs, N);
    mega2_kernel<<<DGB + ATB, 256, 0, stream>>>(
        h1b, attD1, adst1, src, dst, rank, offs, srcs, N, E);
    agg1_kernel<<<(N * 64 + 255) / 256, 256, 0, stream>>>(
        offs, srcs, h1b, attS1, adst1, b1, out1, N);
    gemm2_kernel<<<(N * NC + 255) / 256, 256, 0, stream>>>(out1, W2, h2p, N);
    attn2_kernel<<<(N + 255) / 256, 256, 0, stream>>>(h2p, attS2, attD2, adst2, N);
    agg2_kernel<<<(N * 64 + 255) / 256, 256, 0, stream>>>(offs, srcs, h2p, adst2, b2, out, N);
}

// Round 21
// 409.573 us; speedup vs baseline: 1.1234x; 1.0086x over previous
//
#include <hip/hip_runtime.h>
#include <math.h>

#define NN 100000
#define NE 1600000
#define F_IN 602
#define H1 8
#define C1 8
#define F_MID 64   // H1*C1
#define NC 41
#define H2_LD 48   // padded h2 row: [0..40]=h2, [41]=asrc2
#define NEG_SLOPE 0.2f
#define WT_LD 640  // padded K for bf16 W1-transposed
#define GB1 ((NN + 63) / 64)          // 1563 gemm1 blocks
#define DGB 1024                      // deg/scatter grid-stride blocks
#define ATB ((NN * H1 + 255) / 256)   // 3125 attn1 blocks

#define LRELU(x) fmaxf((x), NEG_SLOPE * (x))

typedef __attribute__((ext_vector_type(8))) short short8;
typedef __attribute__((ext_vector_type(4))) float f32x4;

__device__ inline unsigned short f2bf(float f) {
    unsigned u = __builtin_bit_cast(unsigned, f);
    unsigned r = (u + 0x7FFFu + ((u >> 16) & 1u)) >> 16;
    return (unsigned short)r;
}
__device__ inline float bf2f(unsigned short u) {
    unsigned v = ((unsigned)u) << 16;
    return __builtin_bit_cast(float, v);
}

// -------- fused prep: W1 -> bf16 transposed padded [64][640]  +  zero deg --------
__global__ void prep_kernel(const float* __restrict__ W, unsigned short* __restrict__ Wt,
                            int4* __restrict__ degv, int ndeg4)
{
    int idx = blockIdx.x * blockDim.x + threadIdx.x;
    if (idx < F_MID * WT_LD) {
        int col = idx / WT_LD, k = idx % WT_LD;
        Wt[idx] = (k < F_IN) ? f2bf(W[k * F_MID + col]) : (unsigned short)0;
    } else {
        int z = idx - F_MID * WT_LD;
        if (z < ndeg4) degv[z] = make_int4(0, 0, 0, 0);
    }
}

// ---- MEGA1: deg-histogram+rank (blocks 0..DGB-1) ∥ gemm1 (R13 form: BM=64, BK=32) ----
__global__ __launch_bounds__(256) void mega1_kernel(
    const float* __restrict__ x, const unsigned short* __restrict__ Wt,
    unsigned short* __restrict__ h1b,
    const int* __restrict__ dst, int* __restrict__ deg, int* __restrict__ rank,
    int N, int E)
{
    __shared__ unsigned short As[64][40];  // stride 80B -> <=2-way conflicts
    __shared__ unsigned short Bs[64][40];

    int bid = blockIdx.x;
    int t = threadIdx.x;

    if (bid < DGB) {   // ---- deg path: rank[e] = old count ----
        for (int e = bid * 256 + t; e < E; e += DGB * 256)
            rank[e] = atomicAdd(&deg[dst[e]], 1);
        return;
    }

    // ---- gemm1 path ----
    int lane = t & 63;
    int w = t >> 6;
    int l16 = lane & 15, lg = lane >> 4;
    int n0 = (bid - DGB) * 64;

    int arow = t >> 2, aseg = t & 3;
    int grow = n0 + arow;
    const float* xrow = x + (size_t)(grow < N ? grow : 0) * F_IN + aseg * 8;
    int bcol = t >> 2;
    const unsigned short* wrow = Wt + (size_t)bcol * WT_LD + aseg * 8;

    f32x4 acc[4] = {};
    float2 av[4];
    uint4  bv;

    #pragma unroll
    for (int i = 0; i < 4; ++i) av[i] = *(const float2*)(xrow + i * 2);
    bv = *(const uint4*)(wrow);

    for (int kt = 0; kt < 19; ++kt) {
        __syncthreads();
        {
            unsigned short tmp[8];
            #pragma unroll
            for (int i = 0; i < 4; ++i) {
                tmp[i * 2]     = f2bf(av[i].x);
                tmp[i * 2 + 1] = f2bf(av[i].y);
            }
            *(uint4*)(&As[arow][aseg * 8]) = *(uint4*)tmp;
            *(uint4*)(&Bs[bcol][aseg * 8]) = bv;
        }
        __syncthreads();

        if (kt < 18) {
            int k0 = (kt + 1) * 32;
            if (kt + 1 < 18) {
                #pragma unroll
                for (int i = 0; i < 4; ++i) av[i] = *(const float2*)(xrow + k0 + i * 2);
            } else {
                #pragma unroll
                for (int i = 0; i < 4; ++i) {
                    int k = k0 + aseg * 8 + i * 2;
                    float a = (k < F_IN)     ? xrow[k0 + i * 2]     : 0.f;
                    float b = (k + 1 < F_IN) ? xrow[k0 + i * 2 + 1] : 0.f;
                    av[i] = make_float2(a, b);
                }
            }
            bv = *(const uint4*)(wrow + k0);
        }

        short8 afrag = *(const short8*)(&As[w * 16 + l16][lg * 8]);
        short8 bfrag[4];
        #pragma unroll
        for (int n = 0; n < 4; ++n)
            bfrag[n] = *(const short8*)(&Bs[n * 16 + l16][lg * 8]);
        #pragma unroll
        for (int n = 0; n < 4; ++n)
            acc[n] = __builtin_amdgcn_mfma_f32_16x16x32_bf16(afrag, bfrag[n], acc[n], 0, 0, 0);
    }

    #pragma unroll
    for (int r = 0; r < 4; ++r) {
        int row = n0 + w * 16 + lg * 4 + r;
        if (row < N) {
            #pragma unroll
            for (int n = 0; n < 4; ++n)
                h1b[(size_t)row * F_MID + n * 16 + l16] = f2bf(acc[n][r]);
        }
    }
}

// ---------------- hierarchical scan ----------------
__global__ void scan1_kernel(const int* __restrict__ deg, int* __restrict__ bsum, int N)
{
    int b = blockIdx.x, t = threadIdx.x;
    int base = b * 1024 + t * 16;
    int s = 0;
    #pragma unroll
    for (int i = 0; i < 16; ++i) { int idx = base + i; if (idx < N) s += deg[idx]; }
    #pragma unroll
    for (int o = 32; o > 0; o >>= 1) s += __shfl_down(s, o);
    if (t == 0) bsum[b] = s;
}

__global__ void scan2_kernel(const int* __restrict__ bsum, int* __restrict__ boff,
                             int nb, int* __restrict__ offs, int N, int E)
{
    __shared__ int buf[128];
    int t = threadIdx.x;
    int v = (t < nb) ? bsum[t] : 0;
    buf[t] = v;
    __syncthreads();
    for (int o = 1; o < 128; o <<= 1) {
        int u = (t >= o) ? buf[t - o] : 0;
        __syncthreads();
        buf[t] += u;
        __syncthreads();
    }
    if (t < nb) boff[t] = buf[t] - v;    // exclusive
    if (t == 0) offs[N] = E;
}

__global__ void scan3_kernel(const int* __restrict__ deg, const int* __restrict__ boff,
                             int* __restrict__ offs, int N)
{
    int b = blockIdx.x, t = threadIdx.x;
    int base = b * 1024 + t * 16;
    int loc[16];
    int s = 0;
    #pragma unroll
    for (int i = 0; i < 16; ++i) {
        int idx = base + i;
        loc[i] = (idx < N) ? deg[idx] : 0;
        s += loc[i];
    }
    int inc = s;
    #pragma unroll
    for (int o = 1; o < 64; o <<= 1) {
        int u = __shfl_up(inc, o);
        if (t >= o) inc += u;
    }
    int run = inc - s + boff[b];
    #pragma unroll
    for (int i = 0; i < 16; ++i) {
        int idx = base + i;
        if (idx < N) offs[idx] = run;
        run += loc[i];
    }
}

// ---- MEGA2: rank-based scatter (atomic-free) ∥ attn1 (adst only — asrc computed in agg1) ----
__global__ void mega2_kernel(
    const unsigned short* __restrict__ h1b,
    const float* __restrict__ attD,
    float* __restrict__ adst,
    const int* __restrict__ src, const int* __restrict__ dst,
    const int* __restrict__ rank, const int* __restrict__ offs,
    int* __restrict__ srcs, int N, int E)
{
    int bid = blockIdx.x, t = threadIdx.x;
    if (bid < DGB) {   // scatter
        for (int e = bid * 256 + t; e < E; e += DGB * 256)
            srcs[offs[dst[e]] + rank[e]] = src[e];
        return;
    }
    int idx = (bid - DGB) * 256 + t;   // n*8 + head
    if (idx >= N * H1) return;
    int n = idx >> 3, hh = idx & 7;
    float d = 0.f;
    #pragma unroll
    for (int c = 0; c < C1; ++c)
        d += bf2f(h1b[n * F_MID + hh * C1 + c]) * attD[hh * C1 + c];
    adst[idx] = d;
}

// ------- layer-1 agg + ELU: one wave/node, online softmax, 8-edge batches, bf16 gather,
//         asrc computed IN-WAVE from the gathered row -------
__global__ void agg1_kernel(const int* __restrict__ offs, const int* __restrict__ srcs,
                            const unsigned short* __restrict__ h1b,
                            const float* __restrict__ attS,
                            const float* __restrict__ adst,
                            const float* __restrict__ b1,
                            float* __restrict__ out1, int N)
{
    int wave = (blockIdx.x * blockDim.x + threadIdx.x) >> 6;
    int lane = threadIdx.x & 63;
    if (wave >= N) return;
    int n = wave;
    int hh = lane >> 3;                 // head
    int beg = offs[n], end = offs[n + 1];
    float ad = adst[n * H1 + hh];
    float attv = attS[lane];            // attS1 flat [hh][c] == lane

    float m = -INFINITY, den = 0.f, acc = 0.f;
    int i = beg;
    for (; i + 8 <= end; i += 8) {
        int s[8];
        #pragma unroll
        for (int j = 0; j < 8; ++j) s[j] = srcs[i + j];
        float v[8];
        #pragma unroll
        for (int j = 0; j < 8; ++j) v[j] = bf2f(h1b[(size_t)s[j] * F_MID + lane]);
        float e[8];
        #pragma unroll
        for (int j = 0; j < 8; ++j) {
            float tt = v[j] * attv;          // in-wave asrc: 8-lane head-group reduce
            tt += __shfl_xor(tt, 1);
            tt += __shfl_xor(tt, 2);
            tt += __shfl_xor(tt, 4);
            e[j] = LRELU(tt + ad);
        }
        float m8 = fmaxf(fmaxf(fmaxf(e[0], e[1]), fmaxf(e[2], e[3])),
                         fmaxf(fmaxf(e[4], e[5]), fmaxf(e[6], e[7])));
        float mn = fmaxf(m, m8);
        float sc = __expf(m - mn);
        float p[8];
        #pragma unroll
        for (int j = 0; j < 8; ++j) p[j] = __expf(e[j] - mn);
        den = den * sc + (((p[0] + p[1]) + (p[2] + p[3])) + ((p[4] + p[5]) + (p[6] + p[7])));
        acc = acc * sc + (((p[0] * v[0] + p[1] * v[1]) + (p[2] * v[2] + p[3] * v[3]))
                        + ((p[4] * v[4] + p[5] * v[5]) + (p[6] * v[6] + p[7] * v[7])));
        m = mn;
    }
    for (; i < end; ++i) {
        int s = srcs[i];
        float hv = bf2f(h1b[(size_t)s * F_MID + lane]);
        float tt = hv * attv;
        tt += __shfl_xor(tt, 1);
        tt += __shfl_xor(tt, 2);
        tt += __shfl_xor(tt, 4);
        float e = LRELU(tt + ad);
        float mn = fmaxf(m, e);
        float sc = __expf(m - mn);
        float p  = __expf(e - mn);
        den = den * sc + p;
        acc = acc * sc + p * hv;
        m = mn;
    }
    float inv = 1.f / (den + 1e-16f);
    float v = acc * inv + b1[lane];
    out1[n * F_MID + lane] = v > 0.f ? v : expm1f(v);   // ELU
}

// ---------------- GEMM2: h2p = out1 @ W2  [N,64]x[64,41], row stride 48 ----------------
__global__ __launch_bounds__(256) void gemm2_kernel(
    const float* __restrict__ out1, const float* __restrict__ W2,
    float* __restrict__ h2p, int N)
{
    __shared__ float ws[F_MID * NC];
    for (int i = threadIdx.x; i < F_MID * NC; i += 256) ws[i] = W2[i];
    __syncthreads();
    int idx = blockIdx.x * blockDim.x + threadIdx.x;
    if (idx >= N * NC) return;
    int n = idx / NC, j = idx % NC;
    const float* row = out1 + n * F_MID;
    float acc = 0.f;
    #pragma unroll
    for (int k = 0; k < F_MID; ++k) acc += row[k] * ws[k * NC + j];
    h2p[(size_t)n * H2_LD + j] = acc;
}

// attn2: thread-per-node. asrc -> h2p[n*48+41], adst separate
__global__ void attn2_kernel(float* __restrict__ h2p,
                             const float* __restrict__ attS,
                             const float* __restrict__ attD,
                             float* __restrict__ adst, int N)
{
    int n = blockIdx.x * blockDim.x + threadIdx.x;
    if (n >= N) return;
    float s = 0.f, d = 0.f;
    #pragma unroll
    for (int j = 0; j < NC; ++j) {
        float v = h2p[(size_t)n * H2_LD + j];
        s += v * attS[j];
        d += v * attD[j];
    }
    h2p[(size_t)n * H2_LD + NC] = s;
    adst[n] = d;
}

// ------- layer-2 agg + log_softmax: packed rows, 8-edge batches -------
__global__ void agg2_kernel(const int* __restrict__ offs, const int* __restrict__ srcs,
                            const float* __restrict__ h2p,
                            const float* __restrict__ adst,
                            const float* __restrict__ b2,
                            float* __restrict__ out, int N)
{
    int wave = (blockIdx.x * blockDim.x + threadIdx.x) >> 6;
    int lane = threadIdx.x & 63;
    if (wave >= N) return;
    int n = wave;
    int beg = offs[n], end = offs[n + 1];
    float ad = adst[n];
    bool act = lane < NC;
    int li = act ? lane : NC;           // lanes >=41 read the asrc slot

    float m = -INFINITY, den = 0.f, acc = 0.f;
    int i = beg;
    for (; i + 8 <= end; i += 8) {
        int s[8];
        #pragma unroll
        for (int j = 0; j < 8; ++j) s[j] = srcs[i + j];
        float hv[8];
        #pragma unroll
        for (int j = 0; j < 8; ++j) hv[j] = h2p[(size_t)s[j] * H2_LD + li];
        float a[8];
        #pragma unroll
        for (int j = 0; j < 8; ++j) a[j] = __shfl(hv[j], NC);  // broadcast asrc from lane 41
        float e[8];
        #pragma unroll
        for (int j = 0; j < 8; ++j) e[j] = LRELU(a[j] + ad);
        float m8 = fmaxf(fmaxf(fmaxf(e[0], e[1]), fmaxf(e[2], e[3])),
                         fmaxf(fmaxf(e[4], e[5]), fmaxf(e[6], e[7])));
        float mn = fmaxf(m, m8);
        float sc = __expf(m - mn);
        float p[8];
        #pragma unroll
        for (int j = 0; j < 8; ++j) p[j] = __expf(e[j] - mn);
        den = den * sc + (((p[0] + p[1]) + (p[2] + p[3])) + ((p[4] + p[5]) + (p[6] + p[7])));
        acc = acc * sc + (((p[0] * hv[0] + p[1] * hv[1]) + (p[2] * hv[2] + p[3] * hv[3]))
                        + ((p[4] * hv[4] + p[5] * hv[5]) + (p[6] * hv[6] + p[7] * hv[7])));
        m = mn;
    }
    for (; i < end; ++i) {
        int s = srcs[i];
        float hv = h2p[(size_t)s * H2_LD + li];
        float a = __shfl(hv, NC);
        float e = LRELU(a + ad);
        float mn = fmaxf(m, e);
        float sc = __expf(m - mn);
        float p  = __expf(e - mn);
        den = den * sc + p;
        acc = acc * sc + p * hv;
        m = mn;
    }
    float inv = 1.f / (den + 1e-16f);
    float v = act ? acc * inv + b2[lane] : -INFINITY;
    float mm = v;
    #pragma unroll
    for (int o = 32; o > 0; o >>= 1) mm = fmaxf(mm, __shfl_xor(mm, o));
    float ex = act ? __expf(v - mm) : 0.f;
    float S = ex;
    #pragma unroll
    for (int o = 32; o > 0; o >>= 1) S += __shfl_xor(S, o);
    if (act) out[n * NC + lane] = v - mm - logf(S);
}

// ---------------- launch ----------------
extern "C" void kernel_launch(void* const* d_in, const int* in_sizes, int n_in,
                              void* d_out, int out_size, void* d_ws, size_t ws_size,
                              hipStream_t stream)
{
    const float* x     = (const float*)d_in[0];
    const int*   ei    = (const int*)  d_in[1];
    const float* W1    = (const float*)d_in[2];
    const float* attS1 = (const float*)d_in[3];
    const float* attD1 = (const float*)d_in[4];
    const float* b1    = (const float*)d_in[5];
    const float* W2    = (const float*)d_in[6];
    const float* attS2 = (const float*)d_in[7];
    const float* attD2 = (const float*)d_in[8];
    const float* b2    = (const float*)d_in[9];
    float* out = (float*)d_out;

    const int N = NN, E = NE;
    const int* src = ei;        // edge_index row 0
    const int* dst = ei + E;    // edge_index row 1

    char* p = (char*)d_ws;
    auto alloc = [&](size_t bytes) { char* r = p; p += (bytes + 255) & ~255ull; return r; };
    unsigned short* h1b = (unsigned short*)alloc((size_t)N * F_MID * 2);
    float* adst1 = (float*)alloc((size_t)N * H1 * 4);
    float* out1  = (float*)alloc((size_t)N * F_MID * 4);
    float* h2p   = (float*)alloc((size_t)N * H2_LD * 4);   // [41]=asrc2
    float* adst2 = (float*)alloc((size_t)N * 4);
    int*   deg   = (int*)alloc((size_t)N * 4);
    int*   rank  = (int*)alloc((size_t)E * 4);
    int*   offs  = (int*)alloc((size_t)(N + 1) * 4);
    int*   srcs  = (int*)alloc((size_t)E * 4);
    unsigned short* Wt = (unsigned short*)alloc((size_t)F_MID * WT_LD * 2);
    const int NB = (N + 1023) / 1024;                 // 98 scan blocks
    int*   bsum  = (int*)alloc((size_t)NB * 4);
    int*   boff  = (int*)alloc((size_t)NB * 4);

    const int ndeg4 = N / 4;
    prep_kernel<<<(F_MID * WT_LD + ndeg4 + 255) / 256, 256, 0, stream>>>(
        W1, Wt, (int4*)deg, ndeg4);
    mega1_kernel<<<DGB + GB1, 256, 0, stream>>>(x, Wt, h1b, dst, deg, rank, N, E);
    scan1_kernel<<<NB, 64, 0, stream>>>(deg, bsum, N);
    scan2_kernel<<<1, 128, 0, stream>>>(bsum, boff, NB, offs, N, E);
    scan3_kernel<<<NB, 64, 0, stream>>>(deg, boff, offs, N);
    mega2_kernel<<<DGB + ATB, 256, 0, stream>>>(
        h1b, attD1, adst1, src, dst, rank, offs, srcs, N, E);
    agg1_kernel<<<(N * 64 + 255) / 256, 256, 0, stream>>>(
        offs, srcs, h1b, attS1, adst1, b1, out1, N);
    gemm2_kernel<<<(N * NC + 255) / 256, 256, 0, stream>>>(out1, W2, h2p, N);
    attn2_kernel<<<(N + 255) / 256, 256, 0, stream>>>(h2p, attS2, attD2, adst2, N);
    agg2_kernel<<<(N * 64 + 255) / 256, 256, 0, stream>>>(offs, srcs, h2p, adst2, b2, out, N);
}